// Round 1
// baseline (967.913 us; speedup 1.0000x reference)
//
#include <hip/hip_runtime.h>
#include <math.h>

#define BB 2
#define TT 8192
#define HH 8
#define DD 64
#define NCC 128
#define MM 4
#define WW (TT/NCC)     // 64
#define T2 (2*TT)
#define SA 68           // padded LDS row stride for attention tiles

// ---------------- Kernel A: normalize + cdist + aux(min d2) ----------------
// grid: (T2/256, H, B), block 256. Each thread handles one t' in [0,2T).
__global__ __launch_bounds__(256) void kdist(
    const float* __restrict__ q, const float* __restrict__ k,
    const float* __restrict__ means,
    float* __restrict__ qd, float* __restrict__ kd, float* __restrict__ aux)
{
  __shared__ float sm[NCC * DD];
  __shared__ float sm2[NCC];
  __shared__ float red[4];
  const int b = blockIdx.z, h = blockIdx.y;
  const int tid = threadIdx.x;

  const float4* mp = (const float4*)(means + (size_t)h * NCC * DD);
  float4* smp = (float4*)sm;
  for (int i = tid; i < NCC * DD / 4; i += 256) smp[i] = mp[i];
  __syncthreads();
  if (tid < NCC) {
    float s = 0.f;
    #pragma unroll
    for (int d = 0; d < DD; ++d) { float v = sm[tid * DD + d]; s += v * v; }
    sm2[tid] = s;
  }
  __syncthreads();

  const int tp = blockIdx.x * 256 + tid;               // t' in [0,2T)
  const size_t bh = (size_t)(b * HH + h);
  const float* src = (tp < TT) ? (q + (bh * TT + tp) * DD)
                               : (k + (bh * TT + (tp - TT)) * DD);
  float x[DD];
  float ss = 0.f;
  #pragma unroll
  for (int i = 0; i < DD / 4; ++i) {
    float4 v = ((const float4*)src)[i];
    x[4*i] = v.x; x[4*i+1] = v.y; x[4*i+2] = v.z; x[4*i+3] = v.w;
    ss += v.x*v.x + v.y*v.y + v.z*v.z + v.w*v.w;
  }
  const float scale = 1.f / (sqrtf(ss) + 1e-6f);
  float x2 = 0.f;
  #pragma unroll
  for (int i = 0; i < DD; ++i) { x[i] *= scale; x2 += x[i] * x[i]; }

  float* dst = (tp < TT) ? (qd + (bh * NCC) * TT + tp)
                         : (kd + (bh * NCC) * TT + (tp - TT));
  float mind2 = 1e30f;
  for (int c = 0; c < NCC; ++c) {
    const float* mrow = sm + c * DD;
    float dot = 0.f;
    #pragma unroll
    for (int d = 0; d < DD; ++d) dot += x[d] * mrow[d];
    float d2 = fmaxf(x2 + sm2[c] - 2.f * dot, 0.f);
    mind2 = fminf(mind2, d2);
    dst[(size_t)c * TT] = sqrtf(d2);
  }

  // block-reduce sum of mind2 -> one atomic per block
  float v = mind2;
  #pragma unroll
  for (int off = 32; off; off >>= 1) v += __shfl_down(v, off, 64);
  if ((tid & 63) == 0) red[tid >> 6] = v;
  __syncthreads();
  if (tid == 0) atomicAdd(aux, red[0] + red[1] + red[2] + red[3]);
}

// ---------------- Kernel B: radix-select top-64 smallest per row ----------------
// grid: (NC, H, 2B), block 256. Selects the SET of 64 smallest dists
// (ties at the boundary -> lowest index, matching jax.lax.top_k).
__global__ __launch_bounds__(256) void ktopk(
    const float* __restrict__ qd, const float* __restrict__ kd,
    int* __restrict__ idxq, int* __restrict__ idxk)
{
  __shared__ unsigned int vals[TT];     // 32 KB (float bits; dist>=0 => monotone)
  __shared__ unsigned int hist[256];
  __shared__ unsigned int bc[2];
  __shared__ int outIdx[WW];
  __shared__ unsigned int pos;
  __shared__ int redi[4];

  const int c = blockIdx.x, h = blockIdx.y;
  const int b = blockIdx.z >> 1, isK = blockIdx.z & 1;
  const int tid = threadIdx.x;
  const size_t rowoff = ((size_t)(b * HH + h) * NCC + c) * TT;
  const float* row = (isK ? kd : qd) + rowoff;

  for (int i = tid; i < TT; i += 256) vals[i] = __float_as_uint(row[i]);
  if (tid == 0) pos = 0;
  __syncthreads();

  unsigned int prefix = 0, kk = WW;     // kk = 1-based rank remaining
  for (int shift = 24; shift >= 0; shift -= 8) {
    hist[tid] = 0;
    __syncthreads();
    for (int i = tid; i < TT; i += 256) {
      unsigned int u = vals[i];
      bool m = (shift == 24) || ((u >> (shift + 8)) == prefix);
      if (m) atomicAdd(&hist[(u >> shift) & 255u], 1u);
    }
    __syncthreads();
    if (tid < 64) {
      int h0 = hist[4*tid], h1 = hist[4*tid+1], h2 = hist[4*tid+2], h3 = hist[4*tid+3];
      int s = h0 + h1 + h2 + h3;
      int incl = s;
      #pragma unroll
      for (int off = 1; off < 64; off <<= 1) {
        int t2 = __shfl_up(incl, off, 64);
        if (tid >= off) incl += t2;
      }
      int before = incl - s;
      if (before < (int)kk && (int)kk <= incl) {
        int run = before; unsigned int byte, kn;
        if ((int)kk <= run + h0)      { byte = 4*tid;   kn = kk - run; }
        else { run += h0;
          if ((int)kk <= run + h1)    { byte = 4*tid+1; kn = kk - run; }
          else { run += h1;
            if ((int)kk <= run + h2)  { byte = 4*tid+2; kn = kk - run; }
            else { run += h2;           byte = 4*tid+3; kn = kk - run; } } }
        bc[0] = byte; bc[1] = kn;
      }
    }
    __syncthreads();
    prefix = (prefix << 8) | bc[0];
    kk = bc[1];
    __syncthreads();
  }
  const unsigned int tau = prefix;      // bit pattern of 64th-smallest value
  const int need = (int)kk;             // how many to take from == tau

  for (int i = tid; i < TT; i += 256) {
    if (vals[i] < tau) { unsigned int p = atomicAdd(&pos, 1u); outIdx[p] = i; }
  }
  __syncthreads();
  const int base = (int)pos;            // == 64 - need

  int last = -1;
  for (int e = 0; e < need; ++e) {
    int loc = 0x7fffffff;
    for (int i = tid; i < TT; i += 256)
      if (vals[i] == tau && i > last && i < loc) loc = i;
    #pragma unroll
    for (int off = 32; off; off >>= 1) loc = min(loc, __shfl_down(loc, off, 64));
    if ((tid & 63) == 0) redi[tid >> 6] = loc;
    __syncthreads();
    int winner = min(min(redi[0], redi[1]), min(redi[2], redi[3]));
    if (tid == 0) outIdx[base + e] = winner;
    last = winner;
    __syncthreads();
  }

  int* dst = (isK ? idxk : idxq) + ((size_t)(b * HH + h) * NCC + c) * WW;
  if (tid < WW) dst[tid] = outIdx[tid];
}

// ---------------- Kernel C: gather + attention + atomic scatter ----------------
// grid: (NC, H, B), block 256.
__global__ __launch_bounds__(256) void kattn(
    const float* __restrict__ q, const float* __restrict__ kg,
    const float* __restrict__ vg, const float* __restrict__ memk,
    const float* __restrict__ memv, const int* __restrict__ idxq,
    const int* __restrict__ idxk, float* __restrict__ outp,
    float* __restrict__ denom)
{
  __shared__ float Qs[WW * SA];
  __shared__ float Ks[(MM + WW) * SA];
  __shared__ float Vs[(MM + WW) * SA];
  __shared__ float Ps[WW * SA];
  __shared__ int tq[WW];
  __shared__ int tk[WW];

  const int c = blockIdx.x, h = blockIdx.y, b = blockIdx.z;
  const int tid = threadIdx.x;
  const size_t bh = (size_t)(b * HH + h);

  const int* iq = idxq + (bh * NCC + c) * WW;
  const int* ik = idxk + (bh * NCC + c) * WW;
  if (tid < WW) tq[tid] = iq[tid];
  else if (tid < 2 * WW) tk[tid - WW] = ik[tid - WW];
  __syncthreads();

  const int r = tid >> 2, part = tid & 3;
  // Q gather
  {
    const float* src = q + (bh * TT + tq[r]) * DD + part * 16;
    #pragma unroll
    for (int i = 0; i < 4; ++i)
      *(float4*)&Qs[r * SA + part * 16 + 4 * i] = ((const float4*)src)[i];
  }
  // K/V gather (mem rows first, then clustered rows)
  for (int j = r; j < MM + WW; j += 64) {
    const float* sk = (j < MM)
        ? memk + (((size_t)(h * NCC + c)) * MM + j) * DD + part * 16
        : kg + (bh * TT + tk[j - MM]) * DD + part * 16;
    const float* sv = (j < MM)
        ? memv + (((size_t)(h * NCC + c)) * MM + j) * DD + part * 16
        : vg + (bh * TT + tk[j - MM]) * DD + part * 16;
    #pragma unroll
    for (int i = 0; i < 4; ++i) {
      *(float4*)&Ks[j * SA + part * 16 + 4 * i] = ((const float4*)sk)[i];
      *(float4*)&Vs[j * SA + part * 16 + 4 * i] = ((const float4*)sv)[i];
    }
  }
  __syncthreads();

  // dots + softmax: thread (r, quad) handles 17 of the 68 keys of row r
  float qr[DD];
  #pragma unroll
  for (int i = 0; i < DD; ++i) qr[i] = Qs[r * SA + i];
  float s[17];
  #pragma unroll
  for (int jj = 0; jj < 17; ++jj) {
    const int j = part * 17 + jj;
    const float* krow = &Ks[j * SA];
    float acc = 0.f;
    #pragma unroll
    for (int d = 0; d < DD; ++d) acc += qr[d] * krow[d];
    s[jj] = acc * 0.125f;               // * d^-0.5
  }
  float mx = s[0];
  #pragma unroll
  for (int jj = 1; jj < 17; ++jj) mx = fmaxf(mx, s[jj]);
  mx = fmaxf(mx, __shfl_xor(mx, 1, 64));
  mx = fmaxf(mx, __shfl_xor(mx, 2, 64));
  float sum = 0.f;
  #pragma unroll
  for (int jj = 0; jj < 17; ++jj) { s[jj] = expf(s[jj] - mx); sum += s[jj]; }
  sum += __shfl_xor(sum, 1, 64);
  sum += __shfl_xor(sum, 2, 64);
  const float inv = 1.f / sum;
  #pragma unroll
  for (int jj = 0; jj < 17; ++jj) Ps[r * SA + part * 17 + jj] = s[jj] * inv;
  __syncthreads();

  // out = P @ V : thread (r, dq) computes out[r][dq*16 .. dq*16+15]
  float acc[16];
  #pragma unroll
  for (int i = 0; i < 16; ++i) acc[i] = 0.f;
  const int dq = part;
  for (int j = 0; j < MM + WW; ++j) {
    const float p = Ps[r * SA + j];
    const float* vrow = &Vs[j * SA + dq * 16];
    #pragma unroll
    for (int i = 0; i < 16; ++i) acc[i] += p * vrow[i];
  }
  const int t = tq[r];
  float* obase = outp + (bh * TT + t) * DD + dq * 16;
  #pragma unroll
  for (int i = 0; i < 16; ++i) atomicAdd(obase + i, acc[i]);
  if (dq == 0) atomicAdd(&denom[bh * TT + t], 1.0f);
}

// ---------------- Kernel D: finalize ----------------
__global__ __launch_bounds__(256) void kfinal(
    float* __restrict__ outp, const float* __restrict__ denom,
    const float* __restrict__ aux)
{
  const size_t n = (size_t)BB * HH * TT * DD;
  const size_t i = (size_t)blockIdx.x * 256 + threadIdx.x;
  if (i < n) outp[i] = outp[i] / (denom[i >> 6] + 1e-5f);
  if (i == 0) outp[n] = aux[0] * (0.0001f / (float)((size_t)BB * HH * 2 * TT * DD));
}

extern "C" void kernel_launch(void* const* d_in, const int* in_sizes, int n_in,
                              void* d_out, int out_size, void* d_ws, size_t ws_size,
                              hipStream_t stream) {
  (void)in_sizes; (void)n_in; (void)out_size; (void)ws_size;
  const float* q     = (const float*)d_in[0];
  const float* k     = (const float*)d_in[1];
  const float* v     = (const float*)d_in[2];
  const float* means = (const float*)d_in[3];
  const float* memk  = (const float*)d_in[4];
  const float* memv  = (const float*)d_in[5];
  float* out = (float*)d_out;

  const size_t NQ = (size_t)BB * HH * NCC * TT;     // 16,777,216
  float* qd   = (float*)d_ws;
  float* kd   = qd + NQ;
  int*   idxq = (int*)(kd + NQ);
  int*   idxk = idxq + (size_t)BB * HH * NCC * WW;
  float* den  = (float*)(idxk + (size_t)BB * HH * NCC * WW);
  float* aux  = den + (size_t)BB * HH * TT;

  hipMemsetAsync(out, 0, (size_t)BB * HH * TT * DD * sizeof(float), stream);
  hipMemsetAsync(den, 0, ((size_t)BB * HH * TT + 1) * sizeof(float), stream);

  kdist<<<dim3(T2 / 256, HH, BB), 256, 0, stream>>>(q, k, means, qd, kd, aux);
  ktopk<<<dim3(NCC, HH, 2 * BB), 256, 0, stream>>>(qd, kd, idxq, idxk);
  kattn<<<dim3(NCC, HH, BB), 256, 0, stream>>>(q, k, v, memk, memv, idxq, idxk, out, den);
  const size_t n = (size_t)BB * HH * TT * DD;
  kfinal<<<(n + 255) / 256, 256, 0, stream>>>(out, den, aux);
}

// Round 2
// 594.079 us; speedup vs baseline: 1.6293x; 1.6293x over previous
//
#include <hip/hip_runtime.h>
#include <math.h>

#define BB 2
#define TT 8192
#define HH 8
#define DD 64
#define NCC 128
#define MM 4
#define WW (TT/NCC)     // 64
#define T2 (2*TT)
#define SMAX 32         // slot cap per target row (cnt<=NC=128; overflow path below)
#define SK 65           // padded LDS row stride for K/V tiles

// ---------------- Kernel A: normalize + cdist + aux(min d2) ----------------
// grid: (T2/256, H, B), block 256. Each thread handles one t' in [0,2T).
__global__ __launch_bounds__(256) void kdist(
    const float* __restrict__ q, const float* __restrict__ k,
    const float* __restrict__ means,
    float* __restrict__ qd, float* __restrict__ kd, float* __restrict__ aux)
{
  __shared__ float sm[NCC * DD];
  __shared__ float sm2[NCC];
  __shared__ float red[4];
  const int b = blockIdx.z, h = blockIdx.y;
  const int tid = threadIdx.x;

  const float4* mp = (const float4*)(means + (size_t)h * NCC * DD);
  float4* smp = (float4*)sm;
  for (int i = tid; i < NCC * DD / 4; i += 256) smp[i] = mp[i];
  __syncthreads();
  if (tid < NCC) {
    float s = 0.f;
    #pragma unroll
    for (int d = 0; d < DD; ++d) { float v = sm[tid * DD + d]; s += v * v; }
    sm2[tid] = s;
  }
  __syncthreads();

  const int tp = blockIdx.x * 256 + tid;               // t' in [0,2T)
  const size_t bh = (size_t)(b * HH + h);
  const float* src = (tp < TT) ? (q + (bh * TT + tp) * DD)
                               : (k + (bh * TT + (tp - TT)) * DD);
  float x[DD];
  float ss = 0.f;
  #pragma unroll
  for (int i = 0; i < DD / 4; ++i) {
    float4 v = ((const float4*)src)[i];
    x[4*i] = v.x; x[4*i+1] = v.y; x[4*i+2] = v.z; x[4*i+3] = v.w;
    ss += v.x*v.x + v.y*v.y + v.z*v.z + v.w*v.w;
  }
  const float scale = 1.f / (sqrtf(ss) + 1e-6f);
  float x2 = 0.f;
  #pragma unroll
  for (int i = 0; i < DD; ++i) { x[i] *= scale; x2 += x[i] * x[i]; }

  float* dst = (tp < TT) ? (qd + (bh * NCC) * TT + tp)
                         : (kd + (bh * NCC) * TT + (tp - TT));
  float mind2 = 1e30f;
  for (int c = 0; c < NCC; ++c) {
    const float* mrow = sm + c * DD;
    float dot = 0.f;
    #pragma unroll
    for (int d = 0; d < DD; ++d) dot += x[d] * mrow[d];
    float d2 = fmaxf(x2 + sm2[c] - 2.f * dot, 0.f);
    mind2 = fminf(mind2, d2);
    dst[(size_t)c * TT] = sqrtf(d2);
  }

  float v = mind2;
  #pragma unroll
  for (int off = 32; off; off >>= 1) v += __shfl_down(v, off, 64);
  if ((tid & 63) == 0) red[tid >> 6] = v;
  __syncthreads();
  if (tid == 0) atomicAdd(aux, red[0] + red[1] + red[2] + red[3]);
}

// ---------------- Kernel B: radix-select top-64 smallest per row ----------------
// grid: (NC, H, 2B), block 256. Selects the SET of 64 smallest dists
// (ties at the boundary -> lowest index, matching jax.lax.top_k).
__global__ __launch_bounds__(256) void ktopk(
    const float* __restrict__ qd, const float* __restrict__ kd,
    int* __restrict__ idxq, int* __restrict__ idxk)
{
  __shared__ unsigned int vals[TT];     // 32 KB (float bits; dist>=0 => monotone)
  __shared__ unsigned int hist[256];
  __shared__ unsigned int bc[2];
  __shared__ int outIdx[WW];
  __shared__ unsigned int pos;
  __shared__ int redi[4];

  const int c = blockIdx.x, h = blockIdx.y;
  const int b = blockIdx.z >> 1, isK = blockIdx.z & 1;
  const int tid = threadIdx.x;
  const size_t rowoff = ((size_t)(b * HH + h) * NCC + c) * TT;
  const float* row = (isK ? kd : qd) + rowoff;

  for (int i = tid; i < TT; i += 256) vals[i] = __float_as_uint(row[i]);
  if (tid == 0) pos = 0;
  __syncthreads();

  unsigned int prefix = 0, kk = WW;     // kk = 1-based rank remaining
  for (int shift = 24; shift >= 0; shift -= 8) {
    hist[tid] = 0;
    __syncthreads();
    for (int i = tid; i < TT; i += 256) {
      unsigned int u = vals[i];
      bool m = (shift == 24) || ((u >> (shift + 8)) == prefix);
      if (m) atomicAdd(&hist[(u >> shift) & 255u], 1u);
    }
    __syncthreads();
    if (tid < 64) {
      int h0 = hist[4*tid], h1 = hist[4*tid+1], h2 = hist[4*tid+2], h3 = hist[4*tid+3];
      int s = h0 + h1 + h2 + h3;
      int incl = s;
      #pragma unroll
      for (int off = 1; off < 64; off <<= 1) {
        int t2 = __shfl_up(incl, off, 64);
        if (tid >= off) incl += t2;
      }
      int before = incl - s;
      if (before < (int)kk && (int)kk <= incl) {
        int run = before; unsigned int byte, kn;
        if ((int)kk <= run + h0)      { byte = 4*tid;   kn = kk - run; }
        else { run += h0;
          if ((int)kk <= run + h1)    { byte = 4*tid+1; kn = kk - run; }
          else { run += h1;
            if ((int)kk <= run + h2)  { byte = 4*tid+2; kn = kk - run; }
            else { run += h2;           byte = 4*tid+3; kn = kk - run; } } }
        bc[0] = byte; bc[1] = kn;
      }
    }
    __syncthreads();
    prefix = (prefix << 8) | bc[0];
    kk = bc[1];
    __syncthreads();
  }
  const unsigned int tau = prefix;      // bit pattern of 64th-smallest value
  const int need = (int)kk;             // how many to take from == tau

  for (int i = tid; i < TT; i += 256) {
    if (vals[i] < tau) { unsigned int p = atomicAdd(&pos, 1u); outIdx[p] = i; }
  }
  __syncthreads();
  const int base = (int)pos;            // == 64 - need

  int last = -1;
  for (int e = 0; e < need; ++e) {
    int loc = 0x7fffffff;
    for (int i = tid; i < TT; i += 256)
      if (vals[i] == tau && i > last && i < loc) loc = i;
    #pragma unroll
    for (int off = 32; off; off >>= 1) loc = min(loc, __shfl_down(loc, off, 64));
    if ((tid & 63) == 0) redi[tid >> 6] = loc;
    __syncthreads();
    int winner = min(min(redi[0], redi[1]), min(redi[2], redi[3]));
    if (tid == 0) outIdx[base + e] = winner;
    last = winner;
    __syncthreads();
  }

  int* dst = (isK ? idxk : idxq) + ((size_t)(b * HH + h) * NCC + c) * WW;
  if (tid < WW) dst[tid] = outIdx[tid];
}

// ---------------- Kernel C: gather + attention -> dense per-cluster out ----------------
// grid: (NC, H, B), block 256. No atomics; coalesced float4 stores.
__global__ __launch_bounds__(256) void kattn(
    const float* __restrict__ q, const float* __restrict__ kg,
    const float* __restrict__ vg, const float* __restrict__ memk,
    const float* __restrict__ memv, const int* __restrict__ idxq,
    const int* __restrict__ idxk, float* __restrict__ outc)
{
  __shared__ float Ks[(MM + WW) * SK];   // 68 x 65 floats = 17.7 KB
  __shared__ float Vs[(MM + WW) * SK];
  __shared__ int tq[WW];
  __shared__ int tk[WW];

  const int c = blockIdx.x, h = blockIdx.y, b = blockIdx.z;
  const int tid = threadIdx.x;
  const size_t bh = (size_t)(b * HH + h);

  if (tid < WW) tq[tid] = idxq[(bh * NCC + c) * WW + tid];
  else if (tid < 2 * WW) tk[tid - WW] = idxk[(bh * NCC + c) * WW + tid - WW];
  __syncthreads();

  const int r = tid >> 2, part = tid & 3;

  // K/V gather into LDS (mem rows first, then clustered rows)
  for (int j = r; j < MM + WW; j += 64) {
    const float* sk = (j < MM)
        ? memk + (((size_t)(h * NCC + c)) * MM + j) * DD + part * 16
        : kg + (bh * TT + tk[j - MM]) * DD + part * 16;
    const float* sv = (j < MM)
        ? memv + (((size_t)(h * NCC + c)) * MM + j) * DD + part * 16
        : vg + (bh * TT + tk[j - MM]) * DD + part * 16;
    #pragma unroll
    for (int i = 0; i < 4; ++i) {
      *(float4*)&Ks[j * SK + part * 16 + 4 * i] = ((const float4*)sk)[i];
      *(float4*)&Vs[j * SK + part * 16 + 4 * i] = ((const float4*)sv)[i];
    }
  }
  __syncthreads();

  // dots: thread (r, part) handles keys j in [part*17, part*17+17)
  float s[17];
  {
    float qr[DD];
    const float* qsrc = q + (bh * TT + tq[r]) * DD;
    #pragma unroll
    for (int i = 0; i < DD / 4; ++i) {
      float4 v = ((const float4*)qsrc)[i];
      qr[4*i] = v.x; qr[4*i+1] = v.y; qr[4*i+2] = v.z; qr[4*i+3] = v.w;
    }
    #pragma unroll
    for (int jj = 0; jj < 17; ++jj) {
      const float* krow = &Ks[(part * 17 + jj) * SK];
      float acc = 0.f;
      #pragma unroll
      for (int d = 0; d < DD; ++d) acc += qr[d] * krow[d];
      s[jj] = acc * 0.125f;             // * d^-0.5
    }
  }
  // softmax across the quad (4 lanes = one query row)
  float mx = s[0];
  #pragma unroll
  for (int jj = 1; jj < 17; ++jj) mx = fmaxf(mx, s[jj]);
  mx = fmaxf(mx, __shfl_xor(mx, 1, 64));
  mx = fmaxf(mx, __shfl_xor(mx, 2, 64));
  float sum = 0.f;
  #pragma unroll
  for (int jj = 0; jj < 17; ++jj) { s[jj] = expf(s[jj] - mx); sum += s[jj]; }
  sum += __shfl_xor(sum, 1, 64);
  sum += __shfl_xor(sum, 2, 64);
  const float inv = 1.f / sum;
  #pragma unroll
  for (int jj = 0; jj < 17; ++jj) s[jj] *= inv;

  // PV: each lane accumulates its 17 keys' contribution over all 64 d,
  // then quad-reduce and write the lane's 16-wide slice.
  float acc[DD];
  #pragma unroll
  for (int d = 0; d < DD; ++d) acc[d] = 0.f;
  #pragma unroll
  for (int jj = 0; jj < 17; ++jj) {
    const float p = s[jj];
    const float* vrow = &Vs[(part * 17 + jj) * SK];
    #pragma unroll
    for (int d = 0; d < DD; ++d) acc[d] += p * vrow[d];
  }
  #pragma unroll
  for (int d = 0; d < DD; ++d) {
    acc[d] += __shfl_xor(acc[d], 1, 64);
    acc[d] += __shfl_xor(acc[d], 2, 64);
  }
  float* obase = outc + (((bh * NCC + c) * WW) + r) * DD + part * 16;
  #pragma unroll
  for (int i = 0; i < 4; ++i)
    ((float4*)obase)[i] = make_float4(acc[part*16+4*i], acc[part*16+4*i+1],
                                      acc[part*16+4*i+2], acc[part*16+4*i+3]);
}

// ---------------- Kernel C2: inverted index (one int atomic per selection) ----------------
// grid: B*H*NC*W/256 blocks.
__global__ __launch_bounds__(256) void kindex(
    const int* __restrict__ idxq, const float* __restrict__ outc,
    int* __restrict__ cnt, int* __restrict__ slots, float* __restrict__ out)
{
  const int i = blockIdx.x * 256 + threadIdx.x;       // over B*H*NC*W
  const int bh = i >> 13;                             // NC*W = 8192
  const int e = i & 8191;                             // c*W + w within bh
  const int t = idxq[i];
  const int row = bh * TT + t;
  const int p = atomicAdd(&cnt[row], 1);
  if (p < SMAX) {
    slots[(size_t)row * SMAX + p] = e;
  } else {
    // overflow (cnt>32): structurally possible (<=128), statistically ~never.
    const float* src = outc + ((size_t)(bh * (NCC * WW)) + e) * DD;
    for (int d = 0; d < DD; ++d) atomicAdd(&out[(size_t)row * DD + d], src[d]);
  }
}

// ---------------- Kernel D: gather slots + divide + aux ----------------
__global__ __launch_bounds__(256) void kfinal(
    float* __restrict__ outp, const int* __restrict__ cnt,
    const int* __restrict__ slots, const float* __restrict__ outc,
    const float* __restrict__ aux)
{
  const size_t n = (size_t)BB * HH * TT * DD;
  const size_t i = (size_t)blockIdx.x * 256 + threadIdx.x;
  if (i < n) {
    const int row = (int)(i >> 6);                    // bh*T + t
    const int d = (int)(i & 63);
    const int bh = row >> 13;                         // T = 8192
    const int c = cnt[row];
    const int m = c < SMAX ? c : SMAX;
    float sum = outp[i];                              // overflow accumulations (usually 0)
    for (int s = 0; s < m; ++s) {
      const int e = slots[(size_t)row * SMAX + s];
      sum += outc[((size_t)(bh * (NCC * WW)) + e) * DD + d];
    }
    outp[i] = sum / ((float)c + 1e-5f);
  }
  if (i == 0) outp[n] = aux[0] * (0.0001f / (float)((size_t)BB * HH * 2 * TT * DD));
}

extern "C" void kernel_launch(void* const* d_in, const int* in_sizes, int n_in,
                              void* d_out, int out_size, void* d_ws, size_t ws_size,
                              hipStream_t stream) {
  (void)in_sizes; (void)n_in; (void)out_size; (void)ws_size;
  const float* q     = (const float*)d_in[0];
  const float* k     = (const float*)d_in[1];
  const float* v     = (const float*)d_in[2];
  const float* means = (const float*)d_in[3];
  const float* memk  = (const float*)d_in[4];
  const float* memv  = (const float*)d_in[5];
  float* out = (float*)d_out;

  const size_t NQ   = (size_t)BB * HH * NCC * TT;   // 16,777,216 (dists per side)
  const size_t NIDX = (size_t)BB * HH * NCC * WW;   // 131,072
  const size_t NROW = (size_t)BB * HH * TT;         // 131,072

  float* qd   = (float*)d_ws;
  float* kd   = qd + NQ;
  int*   idxq = (int*)(kd + NQ);
  int*   idxk = idxq + NIDX;
  int*   cnt  = idxk + NIDX;
  float* aux  = (float*)(cnt + NROW);
  // dead after ktopk -> reuse:
  float* outc  = qd;                                // 8,388,608 floats (fits in qd)
  int*   slots = (int*)kd;                          // NROW*SMAX = 4,194,304 ints (fits in kd)

  const size_t n = (size_t)BB * HH * TT * DD;
  hipMemsetAsync(out, 0, n * sizeof(float), stream);
  hipMemsetAsync(cnt, 0, (NROW + 1) * sizeof(int), stream);  // cnt + aux

  kdist<<<dim3(T2 / 256, HH, BB), 256, 0, stream>>>(q, k, means, qd, kd, aux);
  ktopk<<<dim3(NCC, HH, 2 * BB), 256, 0, stream>>>(qd, kd, idxq, idxk);
  kattn<<<dim3(NCC, HH, BB), 256, 0, stream>>>(q, k, v, memk, memv, idxq, idxk, outc);
  kindex<<<(int)(NIDX / 256), 256, 0, stream>>>(idxq, outc, cnt, slots, out);
  kfinal<<<(int)((n + 255) / 256), 256, 0, stream>>>(out, cnt, slots, outc, aux);
}

// Round 6
// 544.679 us; speedup vs baseline: 1.7770x; 1.0907x over previous
//
#include <hip/hip_runtime.h>
#include <math.h>

#define BB 2
#define TT 8192
#define HH 8
#define DD 64
#define NCC 128
#define MM 4
#define WW (TT/NCC)     // 64
#define T2 (2*TT)
#define SMAX 32         // slot cap per target row (cnt<=NC=128; overflow path below)
#define SK 65           // padded LDS row stride for attention tiles

// ---------------- Kernel A: normalize + cdist + aux(min d2) ----------------
// ROUND-2 VERBATIM. The top-64 boundary is fp-sensitive: changing the dot
// contraction (e.g. explicit fmaf interleave, s_load means) changed distance
// bits and flipped selections vs the reference (rounds 3-5 failures). Do NOT
// touch expression forms here without re-validating.
__global__ __launch_bounds__(256) void kdist(
    const float* __restrict__ q, const float* __restrict__ k,
    const float* __restrict__ means,
    float* __restrict__ qd, float* __restrict__ kd, float* __restrict__ aux)
{
  __shared__ float sm[NCC * DD];
  __shared__ float sm2[NCC];
  __shared__ float red[4];
  const int b = blockIdx.z, h = blockIdx.y;
  const int tid = threadIdx.x;

  const float4* mp = (const float4*)(means + (size_t)h * NCC * DD);
  float4* smp = (float4*)sm;
  for (int i = tid; i < NCC * DD / 4; i += 256) smp[i] = mp[i];
  __syncthreads();
  if (tid < NCC) {
    float s = 0.f;
    #pragma unroll
    for (int d = 0; d < DD; ++d) { float v = sm[tid * DD + d]; s += v * v; }
    sm2[tid] = s;
  }
  __syncthreads();

  const int tp = blockIdx.x * 256 + tid;               // t' in [0,2T)
  const size_t bh = (size_t)(b * HH + h);
  const float* src = (tp < TT) ? (q + (bh * TT + tp) * DD)
                               : (k + (bh * TT + (tp - TT)) * DD);
  float x[DD];
  float ss = 0.f;
  #pragma unroll
  for (int i = 0; i < DD / 4; ++i) {
    float4 v = ((const float4*)src)[i];
    x[4*i] = v.x; x[4*i+1] = v.y; x[4*i+2] = v.z; x[4*i+3] = v.w;
    ss += v.x*v.x + v.y*v.y + v.z*v.z + v.w*v.w;
  }
  const float scale = 1.f / (sqrtf(ss) + 1e-6f);
  float x2 = 0.f;
  #pragma unroll
  for (int i = 0; i < DD; ++i) { x[i] *= scale; x2 += x[i] * x[i]; }

  float* dst = (tp < TT) ? (qd + (bh * NCC) * TT + tp)
                         : (kd + (bh * NCC) * TT + (tp - TT));
  float mind2 = 1e30f;
  for (int c = 0; c < NCC; ++c) {
    const float* mrow = sm + c * DD;
    float dot = 0.f;
    #pragma unroll
    for (int d = 0; d < DD; ++d) dot += x[d] * mrow[d];
    float d2 = fmaxf(x2 + sm2[c] - 2.f * dot, 0.f);
    mind2 = fminf(mind2, d2);
    dst[(size_t)c * TT] = sqrtf(d2);
  }

  float v = mind2;
  #pragma unroll
  for (int off = 32; off; off >>= 1) v += __shfl_down(v, off, 64);
  if ((tid & 63) == 0) red[tid >> 6] = v;
  __syncthreads();
  if (tid == 0) atomicAdd(aux, red[0] + red[1] + red[2] + red[3]);
}

// ---------------- Kernel B: top-64 smallest per row ----------------
// grid: (NC, H, 2B), block 256. LDS-resident vals; tau found by bitwise
// binary search (no histogram atomic storms); collect + tie-break are
// round-2's exact validated machinery. Same set semantics as the round-2
// radix version: tau = 64th-smallest pattern, all <tau, lowest-index ties.
__global__ __launch_bounds__(256) void ktopk(
    const float* __restrict__ qd, const float* __restrict__ kd,
    int* __restrict__ idxq, int* __restrict__ idxk)
{
  __shared__ unsigned int vals[TT];     // 32 KB (float bits; dist>=0 => monotone)
  __shared__ unsigned int red[4];
  __shared__ int outIdx[WW];
  __shared__ unsigned int pos;
  __shared__ int redi[4];

  const int c = blockIdx.x, h = blockIdx.y;
  const int b = blockIdx.z >> 1, isK = blockIdx.z & 1;
  const int tid = threadIdx.x;
  const int lane = tid & 63, wid = tid >> 6;
  const size_t rowoff = ((size_t)(b * HH + h) * NCC + c) * TT;
  const float* row = (isK ? kd : qd) + rowoff;

  for (int i = tid; i < TT; i += 256) vals[i] = __float_as_uint(row[i]);
  if (tid == 0) pos = 0;
  __syncthreads();

  // bitwise binary search for the 64th-smallest bit pattern (bit31 sign = 0)
  unsigned int tau = 0u;
  for (int bit = 30; bit >= 0; --bit) {
    const unsigned int cand = tau | (1u << bit);
    int cnt = 0;
    for (int i = tid; i < TT; i += 256) cnt += (vals[i] < cand) ? 1 : 0;
    #pragma unroll
    for (int off = 32; off; off >>= 1) cnt += __shfl_down(cnt, off, 64);
    if (lane == 0) red[wid] = (unsigned int)cnt;
    __syncthreads();
    const int tot = (int)(red[0] + red[1] + red[2] + red[3]);
    if (tot < WW) tau = cand;           // 64th smallest >= cand
    __syncthreads();
  }

  // collect strictly-below (round-2 code)
  for (int i = tid; i < TT; i += 256) {
    if (vals[i] < tau) { unsigned int p = atomicAdd(&pos, 1u); outIdx[p] = i; }
  }
  __syncthreads();
  const int base = (int)pos;            // == 64 - need
  const int need = WW - base;

  // round-2 serial tie selection: lowest `need` indices with vals == tau
  int last = -1;
  for (int e = 0; e < need; ++e) {
    int loc = 0x7fffffff;
    for (int i = tid; i < TT; i += 256)
      if (vals[i] == tau && i > last && i < loc) loc = i;
    #pragma unroll
    for (int off = 32; off; off >>= 1) loc = min(loc, __shfl_down(loc, off, 64));
    if ((tid & 63) == 0) redi[tid >> 6] = loc;
    __syncthreads();
    int winner = min(min(redi[0], redi[1]), min(redi[2], redi[3]));
    if (tid == 0) outIdx[base + e] = winner;
    last = winner;
    __syncthreads();
  }

  int* dstp = (isK ? idxk : idxq) + ((size_t)(b * HH + h) * NCC + c) * WW;
  if (tid < WW) dstp[tid] = outIdx[tid];
}

// ---------------- Kernel C: gather + attention -> dense per-cluster out ----------------
// grid: (NC, H, B), block 256. No atomics; coalesced float4 stores.
__global__ __launch_bounds__(256) void kattn(
    const float* __restrict__ q, const float* __restrict__ kg,
    const float* __restrict__ vg, const float* __restrict__ memk,
    const float* __restrict__ memv, const int* __restrict__ idxq,
    const int* __restrict__ idxk, float* __restrict__ outc)
{
  __shared__ float Ks[(MM + WW) * SK];   // 68 x 65 floats = 17.7 KB
  __shared__ float Vs[(MM + WW) * SK];
  __shared__ int tq[WW];
  __shared__ int tk[WW];

  const int c = blockIdx.x, h = blockIdx.y, b = blockIdx.z;
  const int tid = threadIdx.x;
  const size_t bh = (size_t)(b * HH + h);

  if (tid < WW) tq[tid] = idxq[(bh * NCC + c) * WW + tid];
  else if (tid < 2 * WW) tk[tid - WW] = idxk[(bh * NCC + c) * WW + tid - WW];
  __syncthreads();

  const int r = tid >> 2, part = tid & 3;

  for (int j = r; j < MM + WW; j += 64) {
    const float* sk = (j < MM)
        ? memk + (((size_t)(h * NCC + c)) * MM + j) * DD + part * 16
        : kg + (bh * TT + tk[j - MM]) * DD + part * 16;
    const float* sv = (j < MM)
        ? memv + (((size_t)(h * NCC + c)) * MM + j) * DD + part * 16
        : vg + (bh * TT + tk[j - MM]) * DD + part * 16;
    #pragma unroll
    for (int i = 0; i < 4; ++i) {
      *(float4*)&Ks[j * SK + part * 16 + 4 * i] = ((const float4*)sk)[i];
      *(float4*)&Vs[j * SK + part * 16 + 4 * i] = ((const float4*)sv)[i];
    }
  }
  __syncthreads();

  float s[17];
  {
    float qr[DD];
    const float* qsrc = q + (bh * TT + tq[r]) * DD;
    #pragma unroll
    for (int i = 0; i < DD / 4; ++i) {
      float4 v = ((const float4*)qsrc)[i];
      qr[4*i] = v.x; qr[4*i+1] = v.y; qr[4*i+2] = v.z; qr[4*i+3] = v.w;
    }
    #pragma unroll
    for (int jj = 0; jj < 17; ++jj) {
      const float* krow = &Ks[(part * 17 + jj) * SK];
      float acc = 0.f;
      #pragma unroll
      for (int d = 0; d < DD; ++d) acc += qr[d] * krow[d];
      s[jj] = acc * 0.125f;
    }
  }
  float mx = s[0];
  #pragma unroll
  for (int jj = 1; jj < 17; ++jj) mx = fmaxf(mx, s[jj]);
  mx = fmaxf(mx, __shfl_xor(mx, 1, 64));
  mx = fmaxf(mx, __shfl_xor(mx, 2, 64));
  float sum = 0.f;
  #pragma unroll
  for (int jj = 0; jj < 17; ++jj) { s[jj] = expf(s[jj] - mx); sum += s[jj]; }
  sum += __shfl_xor(sum, 1, 64);
  sum += __shfl_xor(sum, 2, 64);
  const float inv = 1.f / sum;
  #pragma unroll
  for (int jj = 0; jj < 17; ++jj) s[jj] *= inv;

  float acc[DD];
  #pragma unroll
  for (int d = 0; d < DD; ++d) acc[d] = 0.f;
  #pragma unroll
  for (int jj = 0; jj < 17; ++jj) {
    const float p = s[jj];
    const float* vrow = &Vs[(part * 17 + jj) * SK];
    #pragma unroll
    for (int d = 0; d < DD; ++d) acc[d] += p * vrow[d];
  }
  #pragma unroll
  for (int d = 0; d < DD; ++d) {
    acc[d] += __shfl_xor(acc[d], 1, 64);
    acc[d] += __shfl_xor(acc[d], 2, 64);
  }
  float* obase = outc + (((bh * NCC + c) * WW) + r) * DD + part * 16;
  #pragma unroll
  for (int i = 0; i < 4; ++i)
    ((float4*)obase)[i] = make_float4(acc[part*16+4*i], acc[part*16+4*i+1],
                                      acc[part*16+4*i+2], acc[part*16+4*i+3]);
}

// ---------------- Kernel C2: inverted index (one int atomic per selection) ----------------
__global__ __launch_bounds__(256) void kindex(
    const int* __restrict__ idxq, const float* __restrict__ outc,
    int* __restrict__ cnt, int* __restrict__ slots, float* __restrict__ out)
{
  const int i = blockIdx.x * 256 + threadIdx.x;       // over B*H*NC*W
  const int bh = i >> 13;                             // NC*W = 8192
  const int e = i & 8191;
  const int t = idxq[i];
  const int row = bh * TT + t;
  const int p = atomicAdd(&cnt[row], 1);
  if (p < SMAX) {
    slots[(size_t)row * SMAX + p] = e;
  } else {
    const float* src = outc + ((size_t)(bh * (NCC * WW)) + e) * DD;
    for (int d = 0; d < DD; ++d) atomicAdd(&out[(size_t)row * DD + d], src[d]);
  }
}

// ---------------- Kernel D: gather slots + divide + aux ----------------
__global__ __launch_bounds__(256) void kfinal(
    float* __restrict__ outp, const int* __restrict__ cnt,
    const int* __restrict__ slots, const float* __restrict__ outc,
    const float* __restrict__ aux)
{
  const size_t n = (size_t)BB * HH * TT * DD;
  const size_t i = (size_t)blockIdx.x * 256 + threadIdx.x;
  if (i < n) {
    const int row = (int)(i >> 6);
    const int d = (int)(i & 63);
    const int bh = row >> 13;
    const int c = cnt[row];
    const int m = c < SMAX ? c : SMAX;
    float sum = outp[i];
    for (int s = 0; s < m; ++s) {
      const int e = slots[(size_t)row * SMAX + s];
      sum += outc[((size_t)(bh * (NCC * WW)) + e) * DD + d];
    }
    outp[i] = sum / ((float)c + 1e-5f);
  }
  if (i == 0) outp[n] = aux[0] * (0.0001f / (float)((size_t)BB * HH * 2 * TT * DD));
}

extern "C" void kernel_launch(void* const* d_in, const int* in_sizes, int n_in,
                              void* d_out, int out_size, void* d_ws, size_t ws_size,
                              hipStream_t stream) {
  (void)in_sizes; (void)n_in; (void)out_size; (void)ws_size;
  const float* q     = (const float*)d_in[0];
  const float* k     = (const float*)d_in[1];
  const float* v     = (const float*)d_in[2];
  const float* means = (const float*)d_in[3];
  const float* memk  = (const float*)d_in[4];
  const float* memv  = (const float*)d_in[5];
  float* out = (float*)d_out;

  const size_t NQ   = (size_t)BB * HH * NCC * TT;   // 16,777,216
  const size_t NIDX = (size_t)BB * HH * NCC * WW;   // 131,072
  const size_t NROW = (size_t)BB * HH * TT;         // 131,072

  float* qd   = (float*)d_ws;
  float* kd   = qd + NQ;
  int*   idxq = (int*)(kd + NQ);
  int*   idxk = idxq + NIDX;
  int*   cnt  = idxk + NIDX;
  float* aux  = (float*)(cnt + NROW);
  float* outc  = qd;                                // dead after ktopk -> reuse
  int*   slots = (int*)kd;

  const size_t n = (size_t)BB * HH * TT * DD;
  hipMemsetAsync(out, 0, n * sizeof(float), stream);
  hipMemsetAsync(cnt, 0, (NROW + 1) * sizeof(int), stream);  // cnt + aux

  kdist<<<dim3(T2 / 256, HH, BB), 256, 0, stream>>>(q, k, means, qd, kd, aux);
  ktopk<<<dim3(NCC, HH, 2 * BB), 256, 0, stream>>>(qd, kd, idxq, idxk);
  kattn<<<dim3(NCC, HH, BB), 256, 0, stream>>>(q, k, v, memk, memv, idxq, idxk, outc);
  kindex<<<(int)(NIDX / 256), 256, 0, stream>>>(idxq, outc, cnt, slots, out);
  kfinal<<<(int)((n + 255) / 256), 256, 0, stream>>>(out, cnt, slots, outc, aux);
}